// Round 5
// baseline (975.400 us; speedup 1.0000x reference)
//
#include <hip/hip_runtime.h>

// ---------------------------------------------------------------------------
// Fused 4-expert MoE actor:  gate(softmax) -> L1(relu) -> L2(relu) -> head
//   blend commutes into GEMM: sum_e c_e (x@W_e) = [c_e*x]_cat @ vstack(W_e)
// v4: same as v3b but LDS cut 80->64 KB so 2 blocks/CU genuinely co-reside
// (R4 showed 2x81920 exact-fit fails -> 1 block/CU, occupancy 22%).
//   - L1 weight ring: 2 x 16KB slots, issue at top of phase, vmcnt(0)/phase
//   - L2 weight ring: 4 x 8KB slots, counted vmcnt(1)
//   - b1p staged post-softmax (gate overlay owns STG during gate)
//   - head bmu tile lives in dead half of FRAG
// Cross-wave rule: every wave waits its own vmcnt/lgkmcnt BEFORE the barrier.
// ---------------------------------------------------------------------------

typedef _Float16 half8 __attribute__((ext_vector_type(8)));
typedef _Float16 half4v __attribute__((ext_vector_type(4)));
typedef float floatx4 __attribute__((ext_vector_type(4)));

#define MFMA16(a, b, c) __builtin_amdgcn_mfma_f32_16x16x32_f16(a, b, c, 0, 0, 0)
#define WAIT_VM(N) asm volatile("s_waitcnt vmcnt(" #N ")" ::: "memory")
#define WAIT_LGKM0 asm volatile("s_waitcnt lgkmcnt(0)" ::: "memory")

__device__ __forceinline__ void barrier_mem() {
  asm volatile("" ::: "memory");
  __builtin_amdgcn_s_barrier();
  asm volatile("" ::: "memory");
}

__device__ __forceinline__ half8 splat8(_Float16 v) {
  half8 r = {v, v, v, v, v, v, v, v};
  return r;
}

// coeff A-fragment for the K=32 bias tiles (B rows k>=4 are zeroed by prep).
__device__ __forceinline__ half8 make_cfrag(half4v c) {
  half8 r = {c[0], c[1], c[2], c[3], (_Float16)0, (_Float16)0, (_Float16)0, (_Float16)0};
  return r;
}

// global -> LDS direct copy, 16B/lane. LDS dest wave-uniform (HW adds
// lane*16); global src per-lane (+ l*8 halfwords).
__device__ __forceinline__ void load_lds16(const _Float16* g, _Float16* s) {
  __builtin_amdgcn_global_load_lds((__attribute__((address_space(1))) void*)(g),
                                   (__attribute__((address_space(3))) void*)(s), 16, 0, 0);
}

// ---- d_ws halfword offsets (prepped f16 weights, fragment order) ----
// W1P/W2P/WMUP tiles in CONSUMPTION order t: t8 = t>>2, e = t&3 (kstep = e*8+t8)
enum {
  W1P = 0,        // 32 tiles x [16 ct][64 l][8 j] = 262144
  W2P = 262144,   // 32 tiles x [ 8 ct][64 l][8 j] = 131072
  WMUP = 393216,  // 16 tiles x [ 2 ct][64 l][8 j] = 16384
  GW1P = 409600,  //  8 tiles x [ 2 ct][64 l][8 j] = 8192
  GW2P = 417792,  //  1 tile  x [ 2 ct][64 l][8 j] = 1024
  GWOP = 418816,  //  [64 l][8 j] (cols 0-3 = gWo, rest 0) = 512
  B1P = 419328,   //  [16 ct][64][8], k<4 = b1 = 8192
  B2P = 427520,   //  [ 8 ct][64][8], k<4 = b2 = 4096
  BMUP = 431616,  //  [ 2 ct][64][8], k<4,o<17 = bmu = 1024
  GBIASP = 432640,//  [0..31]=gb1 [32..63]=gb2 [64..67]=gbo, pad = 512
  WS_TOTAL = 433152
};

__global__ __launch_bounds__(256) void prep_kernel(
    const float* __restrict__ W1, const float* __restrict__ W2,
    const float* __restrict__ Wmu, const float* __restrict__ gW1,
    const float* __restrict__ gW2, const float* __restrict__ gWo,
    const float* __restrict__ b1, const float* __restrict__ b2,
    const float* __restrict__ bmu, const float* __restrict__ gb1,
    const float* __restrict__ gb2, const float* __restrict__ gbo,
    _Float16* __restrict__ ws) {
  int p = blockIdx.x * 256 + threadIdx.x;
  if (p >= WS_TOTAL) return;
  float v = 0.f;
  if (p < W2P) {  // W1 stacked [1024 k][256 o]
    int t = p >> 13, r = p & 8191;
    int ct = r >> 9, l = (r >> 3) & 63, j = r & 7;
    int o = ct * 16 + (l & 15), krel = ((l >> 4) << 3) + j;
    int t8 = t >> 2, e = t & 3;
    v = W1[(e * 256 + t8 * 32 + krel) * 256 + o];
  } else if (p < WMUP) {  // W2 stacked [1024 k][128 o]
    int q = p - W2P, t = q >> 12, r = q & 4095;
    int ct = r >> 9, l = (r >> 3) & 63, j = r & 7;
    int o = ct * 16 + (l & 15), krel = ((l >> 4) << 3) + j;
    int t8 = t >> 2, e = t & 3;
    v = W2[(e * 256 + t8 * 32 + krel) * 128 + o];
  } else if (p < GW1P) {  // Wmu stacked [512 k][17 o] padded to 32 cols
    int q = p - WMUP, t = q >> 10, r = q & 1023;
    int ct = r >> 9, l = (r >> 3) & 63, j = r & 7;
    int o = ct * 16 + (l & 15), krel = ((l >> 4) << 3) + j;
    int t2 = t >> 2, e = t & 3;
    v = (o < 17) ? Wmu[(e * 128 + t2 * 32 + krel) * 17 + o] : 0.f;
  } else if (p < GW2P) {  // gW1 [256][32]
    int q = p - GW1P, ks = q >> 10, r = q & 1023;
    int ct = r >> 9, l = (r >> 3) & 63, j = r & 7;
    int o = ct * 16 + (l & 15), krel = ((l >> 4) << 3) + j;
    v = gW1[(ks * 32 + krel) * 32 + o];
  } else if (p < GWOP) {  // gW2 [32][32]
    int q = p - GW2P;
    int ct = q >> 9, l = (q >> 3) & 63, j = q & 7;
    int o = ct * 16 + (l & 15), krel = ((l >> 4) << 3) + j;
    v = gW2[krel * 32 + o];
  } else if (p < B1P) {  // gWo [32][4] padded to 16 cols
    int q = p - GWOP;
    int l = (q >> 3) & 63, j = q & 7;
    int o = l & 15, krel = ((l >> 4) << 3) + j;
    v = (o < 4) ? gWo[krel * 4 + o] : 0.f;
  } else if (p < B2P) {  // b1 [4][256]
    int q = p - B1P;
    int ct = q >> 9, l = (q >> 3) & 63, j = q & 7;
    int o = ct * 16 + (l & 15), krel = ((l >> 4) << 3) + j;
    v = (krel < 4) ? b1[krel * 256 + o] : 0.f;
  } else if (p < BMUP) {  // b2 [4][128]
    int q = p - B2P;
    int ct = q >> 9, l = (q >> 3) & 63, j = q & 7;
    int o = ct * 16 + (l & 15), krel = ((l >> 4) << 3) + j;
    v = (krel < 4) ? b2[krel * 128 + o] : 0.f;
  } else if (p < GBIASP) {  // bmu [4][17]
    int q = p - BMUP;
    int ct = q >> 9, l = (q >> 3) & 63, j = q & 7;
    int o = ct * 16 + (l & 15), krel = ((l >> 4) << 3) + j;
    v = (krel < 4 && o < 17) ? bmu[krel * 17 + o] : 0.f;
  } else {  // gate biases
    int q = p - GBIASP;
    v = (q < 32) ? gb1[q] : (q < 64) ? gb2[q - 32] : (q < 68) ? gbo[q - 64] : 0.f;
  }
  ws[p] = (_Float16)v;
}

// LDS map (halfwords), total 32768 hw = 65536 B -> 2 blocks/CU (128 KB < 160).
//  FRAG [0,16384):  activation A-frags [8 t8][4 rt][64 l][8 j]
//                   (x, then h1 same layout; h2 in chunks 0-3; bmup at +8192
//                   during head)
//  STG  [16384,32768): 32 KB = ring-2 x 16KB (L1) / ring-4 x 8KB (L2) /
//                   16 x 2KB Wmu tiles (head); gate overlay during gate phase.
enum {
  STG = 16384,
  GW2L = STG + 8192,   // gate overlay
  GWOL = STG + 9216,
  GBL = STG + 9728,    // gb1@+0 gb2@+32 gbo@+64 (f16)
  SCR1 = STG + 10240,  // gate g1 frags [4 rt][64][8]
  SCR2 = STG + 12288,  // gate g2 frags
  COEF = STG + 14336,  // c [64 rows][4 e] f16
  LDS_HW = 32768
};
static_assert(LDS_HW * 2 == 65536, "LDS must be exactly 64KB");

__global__ __launch_bounds__(512, 4) void actor_kernel(
    const float* __restrict__ x, const _Float16* __restrict__ ws,
    float* __restrict__ out) {
  __shared__ __align__(16) _Float16 lds[LDS_HW];
  const int tid = threadIdx.x;
  const int l = tid & 63;
  const int w = tid >> 6;       // wave 0..7 == N-strip (32 cols L1, 16 cols L2)
  const int l15 = l & 15;
  const int g8 = (l >> 4) << 3;
  const long rowbase = (long)blockIdx.x * 64;
  const floatx4 z4 = {0.f, 0.f, 0.f, 0.f};

  // ---------------- P0: x -> f16 A-frags (wave fills chunk t8 = w) ----------
  {
    const float* xp = x + rowbase * 256 + w * 32 + g8;
#pragma unroll
    for (int rt = 0; rt < 4; ++rt) {
      const float* rr = xp + (rt * 16 + l15) * 256;
      float4 v0 = *(const float4*)rr;
      float4 v1 = *(const float4*)(rr + 4);
      half8 h = {(_Float16)v0.x, (_Float16)v0.y, (_Float16)v0.z, (_Float16)v0.w,
                 (_Float16)v1.x, (_Float16)v1.y, (_Float16)v1.z, (_Float16)v1.w};
      *(half8*)(&lds[w * 2048 + rt * 512 + l * 8]) = h;
    }
  }
  // gate weight chunks (20 x 1KB) into STG overlay
  for (int c = w; c < 20; c += 8) {
    const _Float16* src;
    _Float16* dst;
    if (c < 16) { src = ws + GW1P + c * 512; dst = lds + STG + c * 512; }
    else if (c < 18) { src = ws + GW2P + (c - 16) * 512; dst = lds + GW2L + (c - 16) * 512; }
    else if (c == 18) { src = ws + GWOP; dst = lds + GWOL; }
    else { src = ws + GBIASP; dst = lds + GBL; }
    load_lds16(src + l * 8, dst);
  }
  WAIT_LGKM0;
  WAIT_VM(0);  // own staging landed BEFORE barrier (cross-wave consumers)
  barrier_mem();

  // ---------------- gate stage A: g1 = elu(x@gW1+gb1), all 8 waves ----------
  const int grt = w & 3, gct = w >> 2;
  {
    floatx4 ga = z4;
#pragma unroll
    for (int ks = 0; ks < 8; ++ks) {
      half8 a = *(const half8*)(&lds[ks * 2048 + grt * 512 + l * 8]);
      half8 b = *(const half8*)(&lds[STG + ks * 1024 + gct * 512 + l * 8]);
      ga = MFMA16(a, b, ga);
    }
    const int col = gct * 16 + l15;
    const float bias = (float)lds[GBL + col];
    const int hi4 = ((col >> 3) & 3) << 4, jj = col & 7;
#pragma unroll
    for (int rg = 0; rg < 4; ++rg) {
      float v = ga[rg] + bias;
      v = v > 0.f ? v : (__expf(v) - 1.f);
      lds[SCR1 + grt * 512 + ((4 * (l >> 4) + rg) | hi4) * 8 + jj] = (_Float16)v;
    }
  }
  WAIT_LGKM0;
  barrier_mem();

  // ---------------- gate stage B: g2 = elu(g1@gW2+gb2) ----------------------
  {
    half8 a = *(const half8*)(&lds[SCR1 + grt * 512 + l * 8]);
    half8 b = *(const half8*)(&lds[GW2L + gct * 512 + l * 8]);
    floatx4 g2 = MFMA16(a, b, z4);
    const int col = gct * 16 + l15;
    const float bias = (float)lds[GBL + 32 + col];
    const int hi4 = ((col >> 3) & 3) << 4, jj = col & 7;
#pragma unroll
    for (int rg = 0; rg < 4; ++rg) {
      float v = g2[rg] + bias;
      v = v > 0.f ? v : (__expf(v) - 1.f);
      lds[SCR2 + grt * 512 + ((4 * (l >> 4) + rg) | hi4) * 8 + jj] = (_Float16)v;
    }
  }
  WAIT_LGKM0;
  barrier_mem();

  // ---------------- gate stage C: logits + softmax -> COEF (waves 0-3) ------
  if (gct == 0) {
    half8 a = *(const half8*)(&lds[SCR2 + grt * 512 + l * 8]);
    half8 bo = *(const half8*)(&lds[GWOL + l * 8]);
    floatx4 lg = MFMA16(a, bo, z4);
    const float bze = (l15 < 4) ? (float)lds[GBL + 64 + l15] : 0.f;
#pragma unroll
    for (int rg = 0; rg < 4; ++rg) {
      float v = lg[rg] + bze;
      float m = fmaxf(v, __shfl_xor(v, 1));
      m = fmaxf(m, __shfl_xor(m, 2));
      float eo = __expf(v - m);
      float sden = eo + __shfl_xor(eo, 1);
      sden += __shfl_xor(sden, 2);
      if (l15 < 4)
        lds[COEF + (grt * 16 + 4 * (l >> 4) + rg) * 4 + l15] = (_Float16)(eo / sden);
    }
  }
  WAIT_LGKM0;
  barrier_mem();

  // ---------------- coeffs -> regs (COEF dies after this barrier) -----------
  half4v c4[4];
#pragma unroll
  for (int rt = 0; rt < 4; ++rt)
    c4[rt] = *(const half4v*)(&lds[COEF + (rt * 16 + l15) * 4]);
  WAIT_LGKM0;
  barrier_mem();

  // ---------------- stage b1p -> slot0, L1 tile q0 -> slot1 -----------------
  load_lds16(ws + B1P + w * 512 + l * 8, lds + STG + w * 512);
  load_lds16(ws + B1P + (w + 8) * 512 + l * 8, lds + STG + (w + 8) * 512);
  load_lds16(ws + W1P + w * 512 + l * 8, lds + STG + 8192 + w * 512);
  load_lds16(ws + W1P + (w + 8) * 512 + l * 8, lds + STG + 8192 + (w + 8) * 512);
  WAIT_VM(2);  // b1p landed; q0 in flight
  barrier_mem();

  // ---------------- L1 phase 0: bias MFMA from slot 0 -----------------------
  floatx4 acc[4][2];
  {
    half8 b0 = *(const half8*)(&lds[STG + w * 1024 + l * 8]);
    half8 b1v = *(const half8*)(&lds[STG + w * 1024 + 512 + l * 8]);
#pragma unroll
    for (int rt = 0; rt < 4; ++rt) {
      half8 cf = make_cfrag(c4[rt]);
      acc[rt][0] = MFMA16(cf, b0, z4);
      acc[rt][1] = MFMA16(cf, b1v, z4);
    }
    WAIT_VM(0);  // q0 landed
    barrier_mem();
  }

  // ---------------- L1 main: phases p=1..32, ring-2, vmcnt(0)/phase ---------
  half8 af[4];
#pragma unroll 1
  for (int t8 = 0; t8 < 8; ++t8) {
#pragma unroll
    for (int e = 0; e < 4; ++e) {
      const int p = t8 * 4 + e + 1;  // consumes tile q=p-1 from slot (p&1)
      if (p <= 31) {  // issue tile q=p for phase p+1 into slot ((p+1)&1)
        const _Float16* src = ws + W1P + p * 8192 + l * 8;
        _Float16* dst = lds + STG + ((p + 1) & 1) * 8192;
        load_lds16(src + w * 512, dst + w * 512);
        load_lds16(src + (w + 8) * 512, dst + (w + 8) * 512);
      }
      if (e == 0) {
#pragma unroll
        for (int rt = 0; rt < 4; ++rt)
          af[rt] = *(const half8*)(&lds[t8 * 2048 + rt * 512 + l * 8]);
      }
      const int ss = STG + (p & 1) * 8192;
      half8 b0 = *(const half8*)(&lds[ss + w * 1024 + l * 8]);
      half8 b1v = *(const half8*)(&lds[ss + w * 1024 + 512 + l * 8]);
#pragma unroll
      for (int rt = 0; rt < 4; ++rt) {
        half8 as = af[rt] * splat8(c4[rt][e]);
        acc[rt][0] = MFMA16(as, b0, acc[rt][0]);
        acc[rt][1] = MFMA16(as, b1v, acc[rt][1]);
      }
      WAIT_VM(0);
      barrier_mem();
    }
  }

  // ---------------- h1 = relu(acc) -> frag chunk w; L2 prologue -------------
#pragma unroll
  for (int rt = 0; rt < 4; ++rt)
#pragma unroll
    for (int ct = 0; ct < 2; ++ct) {
      const int c32 = ct * 16 + l15;
      const int hi4 = ((c32 >> 3) & 3) << 4, jj = c32 & 7;
#pragma unroll
      for (int rg = 0; rg < 4; ++rg) {
        float v = acc[rt][ct][rg];
        v = v > 0.f ? v : 0.f;
        lds[w * 2048 + rt * 512 + ((4 * (l >> 4) + rg) | hi4) * 8 + jj] = (_Float16)v;
      }
    }
  // stage b2p -> slot0, q0 -> slot1
  load_lds16(ws + B2P + w * 512 + l * 8, lds + STG + w * 512);
  load_lds16(ws + W2P + w * 512 + l * 8, lds + STG + 4096 + w * 512);
  WAIT_LGKM0;
  WAIT_VM(1);  // b2p landed; q0 in flight
  barrier_mem();

  // ---------------- L2 phase 0: bias MFMA (slot 0); issue q1 ----------------
  floatx4 acc2[4];
  {
    load_lds16(ws + W2P + 4096 + w * 512 + l * 8, lds + STG + 2 * 4096 + w * 512);
    half8 b0 = *(const half8*)(&lds[STG + w * 512 + l * 8]);
#pragma unroll
    for (int rt = 0; rt < 4; ++rt) {
      half8 cf = make_cfrag(c4[rt]);
      acc2[rt] = MFMA16(cf, b0, z4);
    }
    WAIT_VM(1);  // q0 landed
    barrier_mem();
  }

  // ---------------- L2 main: phases p=1..32, ring-4, vmcnt(1) ---------------
#pragma unroll 1
  for (int t8 = 0; t8 < 8; ++t8) {
#pragma unroll
    for (int e = 0; e < 4; ++e) {
      const int p = t8 * 4 + e + 1;  // consumes tile q=p-1 from slot (p&3)
      if (p <= 30)  // issue tile q=p+1 for phase p+2 into slot ((p+2)&3)
        load_lds16(ws + W2P + (p + 1) * 4096 + w * 512 + l * 8,
                   lds + STG + ((p + 2) & 3) * 4096 + w * 512);
      if (e == 0) {
#pragma unroll
        for (int rt = 0; rt < 4; ++rt)
          af[rt] = *(const half8*)(&lds[t8 * 2048 + rt * 512 + l * 8]);
      }
      half8 b0 = *(const half8*)(&lds[STG + (p & 3) * 4096 + w * 512 + l * 8]);
#pragma unroll
      for (int rt = 0; rt < 4; ++rt) {
        half8 as = af[rt] * splat8(c4[rt][e]);
        acc2[rt] = MFMA16(as, b0, acc2[rt]);
      }
      if (p <= 30) { WAIT_VM(1); }
      else if (p == 31) { WAIT_VM(0); }
      barrier_mem();
    }
  }

  // ---------------- h2 = relu(acc2) -> frag chunks 0-3; stage head ----------
  {
    const int c32 = ((w & 1) << 4) | l15;
    const int hi4 = ((c32 >> 3) & 3) << 4, jj = c32 & 7;
#pragma unroll
    for (int rt = 0; rt < 4; ++rt)
#pragma unroll
      for (int rg = 0; rg < 4; ++rg) {
        float v = acc2[rt][rg];
        v = v > 0.f ? v : 0.f;
        lds[(w >> 1) * 2048 + rt * 512 + ((4 * (l >> 4) + rg) | hi4) * 8 + jj] = (_Float16)v;
      }
  }
  // Wmu 16 tiles (32 chunks) -> STG; bmup (2 chunks) -> FRAG+8192
  for (int c = w; c < 32; c += 8)
    load_lds16(ws + WMUP + c * 512 + l * 8, lds + STG + c * 512);
  if (w < 2) load_lds16(ws + BMUP + w * 512 + l * 8, lds + 8192 + w * 512);
  WAIT_LGKM0;
  WAIT_VM(0);
  barrier_mem();

  // ---------------- head: [64,512]@[512,32pad], all 8 waves -----------------
  {
    const int hrt = w & 3, hct = w >> 2;
    half8 cf = make_cfrag(c4[hrt]);
    half8 b = *(const half8*)(&lds[8192 + hct * 512 + l * 8]);
    floatx4 hacc = MFMA16(cf, b, z4);
    half8 ah;
#pragma unroll
    for (int t = 0; t < 16; ++t) {
      if ((t & 3) == 0)
        ah = *(const half8*)(&lds[(t >> 2) * 2048 + hrt * 512 + l * 8]);
      half8 as = ah * splat8(c4[hrt][t & 3]);
      half8 bh = *(const half8*)(&lds[STG + t * 1024 + hct * 512 + l * 8]);
      hacc = MFMA16(as, bh, hacc);
    }
    const int col = hct * 16 + l15;
    if (col < 17) {
#pragma unroll
      for (int rg = 0; rg < 4; ++rg)
        out[(rowbase + hrt * 16 + 4 * (l >> 4) + rg) * 17 + col] = hacc[rg];
    }
  }
}

extern "C" void kernel_launch(void* const* d_in, const int* in_sizes, int n_in,
                              void* d_out, int out_size, void* d_ws, size_t ws_size,
                              hipStream_t stream) {
  const float* x = (const float*)d_in[0];
  const float* W1 = (const float*)d_in[1];
  const float* b1 = (const float*)d_in[2];
  const float* W2 = (const float*)d_in[3];
  const float* b2 = (const float*)d_in[4];
  const float* Wmu = (const float*)d_in[5];
  const float* bmu = (const float*)d_in[6];
  const float* gW1 = (const float*)d_in[7];
  const float* gb1 = (const float*)d_in[8];
  const float* gW2 = (const float*)d_in[9];
  const float* gb2 = (const float*)d_in[10];
  const float* gWo = (const float*)d_in[11];
  const float* gbo = (const float*)d_in[12];
  float* out = (float*)d_out;
  _Float16* ws = (_Float16*)d_ws;

  prep_kernel<<<(WS_TOTAL + 255) / 256, 256, 0, stream>>>(
      W1, W2, Wmu, gW1, gW2, gWo, b1, b2, bmu, gb1, gb2, gbo, ws);
  actor_kernel<<<2048, 512, 0, stream>>>(x, ws, out);
}